// Round 1
// baseline (222.912 us; speedup 1.0000x reference)
//
#include <hip/hip_runtime.h>

// tanh via fast exp: tanh(a) = 1 - 2/(exp(2a)+1)
// Handles +-inf correctly: __expf(-inf)=0 -> -1 ; __expf(inf)=inf -> 1.
__device__ __forceinline__ float fast_tanh(float a) {
    float e = __expf(2.0f * a);
    return 1.0f - __fdividef(2.0f, e + 1.0f);
}

__device__ __forceinline__ float band(float x1) {
    return 0.5f * (fast_tanh(100.0f * (x1 - 0.1f)) -
                   fast_tanh(100.0f * (x1 + 0.1f)) + 2.0f);
}

// Each thread processes one float4 = two (x0,x1) elements.
__global__ void __launch_bounds__(256)
dynsys_kernel(const float4* __restrict__ x, const float* __restrict__ ws,
              float2* __restrict__ out, int n4) {
    int i = blockIdx.x * 256 + threadIdx.x;
    if (i >= n4) return;

    // ws pointer + index are wave-uniform -> compiler emits scalar loads (L2 broadcast)
    float w[10];
#pragma unroll
    for (int k = 0; k < 10; ++k) w[k] = ws[k];

    float4 v = x[i];
    float a0 = v.x, a1 = v.y;
    float b0 = v.z, b1 = v.w;

#pragma unroll
    for (int k = 0; k < 10; ++k) {
        float wk = w[k];
        float na0 = a0 - 0.1f * a1;
        float na1 = 0.1f * a0 + a1 - 0.1f * (a0 * a0 * a0) + 0.1f * (wk * a1);
        float nb0 = b0 - 0.1f * b1;
        float nb1 = 0.1f * b0 + b1 - 0.1f * (b0 * b0 * b0) + 0.1f * (wk * b1);
        a0 = na0; a1 = na1;
        b0 = nb0; b1 = nb1;
    }

    out[i] = make_float2(band(a1), band(b1));
}

extern "C" void kernel_launch(void* const* d_in, const int* in_sizes, int n_in,
                              void* d_out, int out_size, void* d_ws, size_t ws_size,
                              hipStream_t stream) {
    const float4* x = (const float4*)d_in[0];        // [B,2] f32, interleaved
    const float*  ws = (const float*)d_in[1];        // [10] f32
    float2* out = (float2*)d_out;                    // [B] f32, written as pairs

    int n4 = in_sizes[0] / 4;                        // float4 count = B/2
    int blocks = (n4 + 255) / 256;
    dynsys_kernel<<<blocks, 256, 0, stream>>>(x, ws, out, n4);
}

// Round 2
// 208.213 us; speedup vs baseline: 1.0706x; 1.0706x over previous
//
#include <hip/hip_runtime.h>

// out = (tanh(100(x1-0.1)) - tanh(100(x1+0.1)) + 2)/2
//     = 1 + 1/(E+1) - 1/(E*e^-40 + 1),  E = e^{200(x1+0.1)}
// Single v_exp_f32 + two v_rcp_f32. Saturates correctly for +-inf, NaN->NaN.
__device__ __forceinline__ float band(float x1) {
    // 200*log2(e) = 288.53900817779268 ; *0.1 offset = 28.853900817779268
    float E  = __builtin_amdgcn_exp2f(fmaf(288.539008f, x1, 28.8539008f));
    float Eu = E * 4.248354255291589e-18f;   // e^-40
    return 1.0f + __builtin_amdgcn_rcpf(E + 1.0f) - __builtin_amdgcn_rcpf(Eu + 1.0f);
}

// One 10-step trajectory for a single (x0,x1) pair, FMA-canonical.
// w01[k] = 0.1f * ws[k] (prescaled once per thread).
__device__ __forceinline__ void traj(float& a0, float& a1, const float* __restrict__ w01) {
#pragma unroll
    for (int k = 0; k < 10; ++k) {
        float na0 = fmaf(-0.1f, a1, a0);           // x0 - 0.1*x1
        float s   = a0 * a0;
        float c   = s * a0;                        // x0^3
        float t1  = fmaf(0.1f, a0, a1);            // 0.1*x0 + x1
        float t2  = fmaf(-0.1f, c, t1);            // - 0.1*x0^3
        float na1 = fmaf(w01[k], a1, t2);          // + (0.1*w)*x1
        a0 = na0; a1 = na1;
    }
}

// 4 (x0,x1) pairs per thread via two coalesced float4 loads at stride `half`.
__global__ void __launch_bounds__(256)
dynsys_kernel(const float4* __restrict__ x, const float* __restrict__ ws,
              float2* __restrict__ out, int half) {
    int i = blockIdx.x * 256 + threadIdx.x;
    if (i >= half) return;

    float w01[10];
#pragma unroll
    for (int k = 0; k < 10; ++k) w01[k] = 0.1f * ws[k];  // scalar loads (uniform)

    float4 va = x[i];
    float4 vb = x[i + half];

    float a0 = va.x, a1 = va.y; traj(a0, a1, w01);
    float b0 = va.z, b1 = va.w; traj(b0, b1, w01);
    float c0 = vb.x, c1 = vb.y; traj(c0, c1, w01);
    float d0 = vb.z, d1 = vb.w; traj(d0, d1, w01);

    out[i]        = make_float2(band(a1), band(b1));
    out[i + half] = make_float2(band(c1), band(d1));
}

extern "C" void kernel_launch(void* const* d_in, const int* in_sizes, int n_in,
                              void* d_out, int out_size, void* d_ws, size_t ws_size,
                              hipStream_t stream) {
    const float4* x  = (const float4*)d_in[0];   // [B,2] f32 = B/2 float4s
    const float*  ws = (const float*)d_in[1];    // [10] f32
    float2* out = (float2*)d_out;                // [B] f32 = B/2 float2s

    int n4   = in_sizes[0] / 4;                  // float4 count = B/2
    int half = n4 / 2;                           // 2 float4s per thread
    int blocks = (half + 255) / 256;
    dynsys_kernel<<<blocks, 256, 0, stream>>>(x, ws, out, half);
}